// Round 2
// baseline (905.746 us; speedup 1.0000x reference)
//
#include <hip/hip_runtime.h>
#include <hip/hip_bf16.h>
#include <stdint.h>

#define N_NODES 50000
#define N_EDGES 800000
#define N_GRAPHS 512

// ---------- helpers ----------
__device__ __forceinline__ unsigned f2sort(float f) {
    unsigned u = __float_as_uint(f);
    return (u & 0x80000000u) ? ~u : (u | 0x80000000u);   // monotonic f32 -> u32
}
__device__ __forceinline__ float sort2f(unsigned u) {
    return __uint_as_float((u & 0x80000000u) ? (u ^ 0x80000000u) : ~u);
}

// ---------- K0: init workspace state ----------
__global__ __launch_bounds__(256) void k0_init(unsigned char* __restrict__ keep,
                                               unsigned char* __restrict__ flagC,
                                               unsigned char* __restrict__ flagS,
                                               unsigned* __restrict__ deg,
                                               unsigned* __restrict__ cursor,
                                               unsigned* __restrict__ minmax) {
    int i = blockIdx.x * 256 + threadIdx.x;
    if (i < N_EDGES) keep[i] = 0;
    if (i < N_NODES) { flagC[i] = 0; flagS[i] = 0; }
    if (i < N_GRAPHS) { deg[i] = 0; cursor[i] = 0; }
    if (i == 0) { minmax[0] = 0xFFFFFFFFu; minmax[1] = 0u; }
}

// ---------- K1: PQ = emb @ [W1a | W1b]  (+ b1 folded into P half) ----------
// PQ[v][j]   (j<256)  = sum_i emb[v][i]*W1[i][j] + b1[j]
// PQ[v][256+j]        = sum_i emb[v][i]*W1[64+i][j]
__global__ __launch_bounds__(256) void k1_gemm(const float* __restrict__ emb,
                                               const float* __restrict__ W1,
                                               const float* __restrict__ b1,
                                               float* __restrict__ PQ) {
    __shared__ float As[64][68];    // [k][r], padded
    __shared__ float Bs[64][128];   // [k][c]
    const int tid = threadIdx.x;
    const int v0  = blockIdx.x * 64;
    const int cy  = blockIdx.y;     // 0..3 -> global cols cy*128..+127

    // stage A (transpose emb tile into [k][r])
    if (v0 + 64 <= N_NODES) {
        const float* srcA = emb + (size_t)v0 * 64;
        for (int idx = tid * 4; idx < 4096; idx += 1024) {
            float4 x = *(const float4*)(srcA + idx);
            int r = idx >> 6, k = idx & 63;
            As[k + 0][r] = x.x; As[k + 1][r] = x.y; As[k + 2][r] = x.z; As[k + 3][r] = x.w;
        }
    } else {
        for (int idx = tid * 4; idx < 4096; idx += 1024) {
            int r = idx >> 6, k = idx & 63;
            int v = v0 + r; if (v >= N_NODES) v = N_NODES - 1;
            float4 x = *(const float4*)(emb + (size_t)v * 64 + k);
            As[k + 0][r] = x.x; As[k + 1][r] = x.y; As[k + 2][r] = x.z; As[k + 3][r] = x.w;
        }
    }
    // stage B (gather the right W1 rows for this col tile)
    for (int idx = tid * 4; idx < 64 * 128; idx += 1024) {
        int k = idx >> 7, c = idx & 127;
        int jj = cy * 128 + c;
        const float* src = (jj < 256) ? (W1 + (size_t)k * 256 + jj)
                                      : (W1 + (size_t)(64 + k) * 256 + (jj - 256));
        *(float4*)&Bs[k][c] = *(const float4*)src;
    }
    __syncthreads();

    const int cgrp = tid & 31;   // 32 col groups * 4 cols
    const int rgrp = tid >> 5;   // 8 row groups * 8 rows
    float acc[8][4];
    #pragma unroll
    for (int r = 0; r < 8; ++r) { acc[r][0]=0.f; acc[r][1]=0.f; acc[r][2]=0.f; acc[r][3]=0.f; }

    #pragma unroll 8
    for (int k = 0; k < 64; ++k) {
        float4 b = *(const float4*)&Bs[k][cgrp * 4];
        const float4* ap = (const float4*)&As[k][rgrp * 8];
        float4 a01 = ap[0], a23 = ap[1];
        float av[8] = {a01.x, a01.y, a01.z, a01.w, a23.x, a23.y, a23.z, a23.w};
        #pragma unroll
        for (int r = 0; r < 8; ++r) {
            acc[r][0] = fmaf(av[r], b.x, acc[r][0]);
            acc[r][1] = fmaf(av[r], b.y, acc[r][1]);
            acc[r][2] = fmaf(av[r], b.z, acc[r][2]);
            acc[r][3] = fmaf(av[r], b.w, acc[r][3]);
        }
    }

    const int jj0 = cy * 128 + cgrp * 4;
    float4 badd = {0.f, 0.f, 0.f, 0.f};
    if (jj0 < 256) badd = *(const float4*)(b1 + jj0);
    #pragma unroll
    for (int r = 0; r < 8; ++r) {
        int v = v0 + rgrp * 8 + r;
        if (v < N_NODES) {
            float4 o = {acc[r][0] + badd.x, acc[r][1] + badd.y,
                        acc[r][2] + badd.z, acc[r][3] + badd.w};
            *(float4*)(PQ + (size_t)v * 512 + jj0) = o;
        }
    }
}

// ---------- K2: per-edge attention score (wave per edge) + histogram + min/max ----------
__global__ __launch_bounds__(256) void k2_edge(const float* __restrict__ PQ,
                                               const int* __restrict__ ei,
                                               const int* __restrict__ batch,
                                               const float* __restrict__ W2,
                                               const float* __restrict__ b2,
                                               float* __restrict__ att,
                                               unsigned* __restrict__ deg,
                                               unsigned* __restrict__ minmax) {
    __shared__ unsigned hist[512];
    const int tid = threadIdx.x;
    hist[tid] = 0; hist[tid + 256] = 0;
    __syncthreads();

    const int lane = tid & 63;
    const int wid  = (blockIdx.x * 256 + tid) >> 6;
    const int nw   = (gridDim.x * 256) >> 6;
    const int j0   = lane * 4;
    const float4 w2v = *(const float4*)(W2 + j0);
    const float b2v = b2[0];
    float vmin = __builtin_inff(), vmax = -__builtin_inff();

    for (int e = wid; e < N_EDGES; e += nw) {
        int r = ei[e], c = ei[N_EDGES + e];
        float4 p = *(const float4*)(PQ + (size_t)r * 512 + j0);
        float4 q = *(const float4*)(PQ + (size_t)c * 512 + 256 + j0);
        float s0 = fmaxf(p.x + q.x, 0.f);
        float s1 = fmaxf(p.y + q.y, 0.f);
        float s2 = fmaxf(p.z + q.z, 0.f);
        float s3 = fmaxf(p.w + q.w, 0.f);
        float part = fmaf(s3, w2v.w, fmaf(s2, w2v.z, fmaf(s1, w2v.y, s0 * w2v.x)));
        #pragma unroll
        for (int off = 32; off; off >>= 1) part += __shfl_xor(part, off, 64);
        float a = part + b2v;
        vmin = fminf(vmin, a); vmax = fmaxf(vmax, a);
        if (lane == 0) {
            att[e] = a;
            atomicAdd(&hist[batch[r]], 1u);
        }
    }
    if (lane == 0) {
        atomicMin(&minmax[0], f2sort(vmin));
        atomicMax(&minmax[1], f2sort(vmax));
    }
    __syncthreads();
    atomicAdd(&deg[tid],       hist[tid]);
    atomicAdd(&deg[tid + 256], hist[tid + 256]);
}

// ---------- K2b: fallback direct per-edge MLP (if ws too small for PQ) ----------
__global__ __launch_bounds__(256) void k2b_edge(const float* __restrict__ emb,
                                                const int* __restrict__ ei,
                                                const int* __restrict__ batch,
                                                const float* __restrict__ W1,
                                                const float* __restrict__ b1,
                                                const float* __restrict__ W2,
                                                const float* __restrict__ b2,
                                                float* __restrict__ att,
                                                unsigned* __restrict__ deg,
                                                unsigned* __restrict__ minmax) {
    __shared__ unsigned hist[512];
    const int tid = threadIdx.x;
    hist[tid] = 0; hist[tid + 256] = 0;
    __syncthreads();
    const int lane = tid & 63;
    const int wid  = (blockIdx.x * 256 + tid) >> 6;
    const int nw   = (gridDim.x * 256) >> 6;
    const int j0   = lane * 4;
    const float4 w2v = *(const float4*)(W2 + j0);
    const float4 b1v = *(const float4*)(b1 + j0);
    const float b2v = b2[0];
    float vmin = __builtin_inff(), vmax = -__builtin_inff();

    for (int e = wid; e < N_EDGES; e += nw) {
        int r = ei[e], c = ei[N_EDGES + e];
        float xlo = emb[(size_t)r * 64 + lane];
        float xhi = emb[(size_t)c * 64 + lane];
        float4 acc = b1v;
        for (int i = 0; i < 64; ++i) {
            float xi = __shfl(xlo, i, 64);
            float4 w = *(const float4*)(W1 + (size_t)i * 256 + j0);
            acc.x = fmaf(xi, w.x, acc.x); acc.y = fmaf(xi, w.y, acc.y);
            acc.z = fmaf(xi, w.z, acc.z); acc.w = fmaf(xi, w.w, acc.w);
        }
        for (int i = 0; i < 64; ++i) {
            float xi = __shfl(xhi, i, 64);
            float4 w = *(const float4*)(W1 + (size_t)(64 + i) * 256 + j0);
            acc.x = fmaf(xi, w.x, acc.x); acc.y = fmaf(xi, w.y, acc.y);
            acc.z = fmaf(xi, w.z, acc.z); acc.w = fmaf(xi, w.w, acc.w);
        }
        float s0 = fmaxf(acc.x, 0.f), s1 = fmaxf(acc.y, 0.f);
        float s2 = fmaxf(acc.z, 0.f), s3 = fmaxf(acc.w, 0.f);
        float part = fmaf(s3, w2v.w, fmaf(s2, w2v.z, fmaf(s1, w2v.y, s0 * w2v.x)));
        #pragma unroll
        for (int off = 32; off; off >>= 1) part += __shfl_xor(part, off, 64);
        float a = part + b2v;
        vmin = fminf(vmin, a); vmax = fmaxf(vmax, a);
        if (lane == 0) {
            att[e] = a;
            atomicAdd(&hist[batch[r]], 1u);
        }
    }
    if (lane == 0) {
        atomicMin(&minmax[0], f2sort(vmin));
        atomicMax(&minmax[1], f2sort(vmax));
    }
    __syncthreads();
    atomicAdd(&deg[tid],       hist[tid]);
    atomicAdd(&deg[tid + 256], hist[tid + 256]);
}

// ---------- K3: scan over 512 graph degrees ----------
__global__ __launch_bounds__(512) void k3_scan(const unsigned* __restrict__ deg,
                                               unsigned* __restrict__ start,
                                               unsigned* __restrict__ kk) {
    __shared__ unsigned lds[512];
    int t = threadIdx.x;
    unsigned d = deg[t];
    lds[t] = d;
    for (int off = 1; off < 512; off <<= 1) {
        __syncthreads();
        unsigned v = (t >= off) ? lds[t - off] : 0u;
        __syncthreads();
        lds[t] += v;
    }
    __syncthreads();
    start[t] = lds[t] - d;        // exclusive prefix
    kk[t]    = (d + 1u) >> 1;     // ceil(0.5*deg)
}

// ---------- K4: scatter edges into per-graph buckets with sortable keys ----------
__global__ __launch_bounds__(256) void k4_scatter(const float* __restrict__ att,
                                                  const int* __restrict__ ei,
                                                  const int* __restrict__ batch,
                                                  const unsigned* __restrict__ start,
                                                  unsigned* __restrict__ cursor,
                                                  const unsigned* __restrict__ minmax,
                                                  unsigned long long* __restrict__ bucket) {
    int e = blockIdx.x * 256 + threadIdx.x;
    if (e >= N_EDGES) return;
    float fmin = sort2f(minmax[0]);
    float fmax = sort2f(minmax[1]);
    float denom = (fmax - fmin) + 1e-12f;
    int g = batch[ei[e]];
    float nq = (att[e] - fmin) / denom;        // replicate ref f32 division
    float mq = nq - (float)g;                  // replicate ref's quantizing subtraction
    unsigned key = ~f2sort(mq);                // descending mq under ascending sort
    unsigned pos = atomicAdd(&cursor[g], 1u);
    bucket[start[g] + pos] = ((unsigned long long)key << 32) | (unsigned)e;
}

// ---------- K5: per-graph bitonic sort (up to 4096) + mark top-k ----------
__global__ __launch_bounds__(256) void k5_sort(const unsigned* __restrict__ deg,
                                               const unsigned* __restrict__ start,
                                               const unsigned* __restrict__ kk,
                                               const unsigned long long* __restrict__ bucket,
                                               unsigned char* __restrict__ keep) {
    __shared__ unsigned long long key[4096];
    const int g = blockIdx.x, t = threadIdx.x;
    unsigned n = deg[g]; if (n > 4096u) n = 4096u;
    const int NS = (n <= 2048u) ? 2048 : 4096;   // adaptive network size
    const unsigned st = start[g];
    for (int i = t; i < NS; i += 256)
        key[i] = ((unsigned)i < n) ? bucket[st + i] : ~0ULL;
    int K = (int)kk[g]; if (K > (int)n) K = (int)n;

    for (int size = 2; size <= NS; size <<= 1)
        for (int stride = size >> 1; stride > 0; stride >>= 1) {
            __syncthreads();
            for (int i = t; i < NS; i += 256) {
                int p = i ^ stride;
                if (p > i) {
                    bool up = ((i & size) == 0);
                    unsigned long long a = key[i], b = key[p];
                    if ((a > b) == up) { key[i] = b; key[p] = a; }
                }
            }
        }
    __syncthreads();
    for (int i = t; i < K; i += 256)
        keep[(unsigned)(key[i] & 0xFFFFFFFFull)] = 1;
}

// ---------- K6: endpoint flags for both subgraphs ----------
__global__ __launch_bounds__(256) void k6_flags(const unsigned char* __restrict__ keep,
                                                const int* __restrict__ ei,
                                                unsigned char* __restrict__ flagC,
                                                unsigned char* __restrict__ flagS) {
    int e = blockIdx.x * 256 + threadIdx.x;
    if (e >= N_EDGES) return;
    int r = ei[e], c = ei[N_EDGES + e];
    if (keep[e]) { flagC[r] = 1; flagC[c] = 1; }
    else         { flagS[r] = 1; flagS[c] = 1; }
}

// ---------- K7: node-id compaction scan (block 0 = causal, block 1 = spurious) ----------
__global__ __launch_bounds__(1024) void k7_nodescan(const unsigned char* __restrict__ flagC,
                                                    const unsigned char* __restrict__ flagS,
                                                    int* __restrict__ nidxC,
                                                    int* __restrict__ nidxS) {
    const unsigned char* fl = blockIdx.x ? flagS : flagC;
    int* nx = blockIdx.x ? nidxS : nidxC;
    __shared__ int lds[1024];
    const int t = threadIdx.x;
    const int CH = (N_NODES + 1023) / 1024;   // 49
    const int base = t * CH;
    int s = 0;
    for (int i = 0; i < CH; ++i) { int v = base + i; if (v < N_NODES) s += fl[v]; }
    lds[t] = s;
    for (int off = 1; off < 1024; off <<= 1) {
        __syncthreads();
        int v = (t >= off) ? lds[t - off] : 0;
        __syncthreads();
        lds[t] += v;
    }
    __syncthreads();
    int run = lds[t] - s;   // exclusive prefix
    for (int i = 0; i < CH; ++i) {
        int v = base + i;
        if (v < N_NODES) {
            if (fl[v]) { nx[v] = run; run++; } else nx[v] = -1;
        }
    }
}

// ---------- K8: write all outputs (as float32 values) ----------
__global__ __launch_bounds__(256) void k8_out(const float* __restrict__ att,
                                              const unsigned char* __restrict__ keep,
                                              const int* __restrict__ ei,
                                              const int* __restrict__ nidxC,
                                              const int* __restrict__ nidxS,
                                              float* __restrict__ out) {
    int e = blockIdx.x * 256 + threadIdx.x;
    if (e >= N_EDGES) return;
    float a = att[e];
    int kp = keep[e];
    int r = ei[e], c = ei[N_EDGES + e];
    out[e]                = a;
    out[N_EDGES + e]      = kp ? a : 0.f;
    out[2 * N_EDGES + e]  = kp ? 0.f : -a;
    out[3 * N_EDGES + e]  = kp ? (float)nidxC[r] : -1.f;
    out[4 * N_EDGES + e]  = kp ? (float)nidxC[c] : -1.f;
    out[5 * N_EDGES + e]  = kp ? -1.f : (float)nidxS[r];
    out[6 * N_EDGES + e]  = kp ? -1.f : (float)nidxS[c];
}

extern "C" void kernel_launch(void* const* d_in, const int* in_sizes, int n_in,
                              void* d_out, int out_size, void* d_ws, size_t ws_size,
                              hipStream_t stream) {
    const float* emb   = (const float*)d_in[0];
    const int*   ei    = (const int*)d_in[1];
    const int*   batch = (const int*)d_in[2];
    const float* W1    = (const float*)d_in[3];
    const float* b1    = (const float*)d_in[4];
    const float* W2    = (const float*)d_in[5];
    const float* b2    = (const float*)d_in[6];
    float* out = (float*)d_out;

    char* ws = (char*)d_ws;
    size_t off = 0;
    auto alloc = [&](size_t bytes) -> void* {
        off = (off + 255) & ~(size_t)255;
        void* p = ws + off;
        off += bytes;
        return p;
    };

    const size_t pq_bytes = (size_t)N_NODES * 512 * 4;   // 102.4 MB
    const bool fast = (ws_size >= pq_bytes + (size_t)20 * 1024 * 1024);

    float* PQ = fast ? (float*)alloc(pq_bytes) : nullptr;
    float* att               = (float*)alloc((size_t)N_EDGES * 4);
    unsigned long long* bucket = (unsigned long long*)alloc((size_t)N_EDGES * 8);
    unsigned char* keep      = (unsigned char*)alloc(N_EDGES);
    unsigned char* flagC     = (unsigned char*)alloc(N_NODES);
    unsigned char* flagS     = (unsigned char*)alloc(N_NODES);
    int* nidxC               = (int*)alloc((size_t)N_NODES * 4);
    int* nidxS               = (int*)alloc((size_t)N_NODES * 4);
    unsigned* deg            = (unsigned*)alloc(512 * 4);
    unsigned* start          = (unsigned*)alloc(512 * 4);
    unsigned* kk             = (unsigned*)alloc(512 * 4);
    unsigned* cursor         = (unsigned*)alloc(512 * 4);
    unsigned* minmax         = (unsigned*)alloc(8);

    const int EB = (N_EDGES + 255) / 256;   // 3125

    k0_init<<<EB, 256, 0, stream>>>(keep, flagC, flagS, deg, cursor, minmax);

    if (fast) {
        dim3 g1((N_NODES + 63) / 64, 4);
        k1_gemm<<<g1, 256, 0, stream>>>(emb, W1, b1, PQ);
        k2_edge<<<2048, 256, 0, stream>>>(PQ, ei, batch, W2, b2, att, deg, minmax);
    } else {
        k2b_edge<<<2048, 256, 0, stream>>>(emb, ei, batch, W1, b1, W2, b2, att, deg, minmax);
    }
    k3_scan<<<1, 512, 0, stream>>>(deg, start, kk);
    k4_scatter<<<EB, 256, 0, stream>>>(att, ei, batch, start, cursor, minmax, bucket);
    k5_sort<<<N_GRAPHS, 256, 0, stream>>>(deg, start, kk, bucket, keep);
    k6_flags<<<EB, 256, 0, stream>>>(keep, ei, flagC, flagS);
    k7_nodescan<<<2, 1024, 0, stream>>>(flagC, flagS, nidxC, nidxS);
    k8_out<<<EB, 256, 0, stream>>>(att, keep, ei, nidxC, nidxS, out);
}

// Round 3
// 858.556 us; speedup vs baseline: 1.0550x; 1.0550x over previous
//
#include <hip/hip_runtime.h>
#include <hip/hip_bf16.h>
#include <stdint.h>

#define N_NODES 50000
#define N_EDGES 800000
#define N_GRAPHS 512

// ---------- helpers ----------
__device__ __forceinline__ unsigned f2sort(float f) {
    unsigned u = __float_as_uint(f);
    return (u & 0x80000000u) ? ~u : (u | 0x80000000u);   // monotonic f32 -> u32
}
__device__ __forceinline__ float sort2f(unsigned u) {
    return __uint_as_float((u & 0x80000000u) ? (u ^ 0x80000000u) : ~u);
}

// ---------- K0: init workspace state (keep is fully written by k5 now) ----------
__global__ __launch_bounds__(256) void k0_init(unsigned char* __restrict__ flagC,
                                               unsigned char* __restrict__ flagS,
                                               unsigned* __restrict__ deg,
                                               unsigned* __restrict__ cursor,
                                               unsigned* __restrict__ minmax) {
    int i = blockIdx.x * 256 + threadIdx.x;
    if (i < N_NODES) { flagC[i] = 0; flagS[i] = 0; }
    if (i < N_GRAPHS) { deg[i] = 0; cursor[i] = 0; }
    if (i == 0) { minmax[0] = 0xFFFFFFFFu; minmax[1] = 0u; }
}

// ---------- K1: PQ = emb @ [W1a | W1b]  (+ b1 folded into P half) ----------
__global__ __launch_bounds__(256) void k1_gemm(const float* __restrict__ emb,
                                               const float* __restrict__ W1,
                                               const float* __restrict__ b1,
                                               float* __restrict__ PQ) {
    __shared__ float As[64][68];    // [k][r], padded
    __shared__ float Bs[64][128];   // [k][c]
    const int tid = threadIdx.x;
    const int v0  = blockIdx.x * 64;
    const int cy  = blockIdx.y;     // 0..3 -> global cols cy*128..+127

    if (v0 + 64 <= N_NODES) {
        const float* srcA = emb + (size_t)v0 * 64;
        for (int idx = tid * 4; idx < 4096; idx += 1024) {
            float4 x = *(const float4*)(srcA + idx);
            int r = idx >> 6, k = idx & 63;
            As[k + 0][r] = x.x; As[k + 1][r] = x.y; As[k + 2][r] = x.z; As[k + 3][r] = x.w;
        }
    } else {
        for (int idx = tid * 4; idx < 4096; idx += 1024) {
            int r = idx >> 6, k = idx & 63;
            int v = v0 + r; if (v >= N_NODES) v = N_NODES - 1;
            float4 x = *(const float4*)(emb + (size_t)v * 64 + k);
            As[k + 0][r] = x.x; As[k + 1][r] = x.y; As[k + 2][r] = x.z; As[k + 3][r] = x.w;
        }
    }
    for (int idx = tid * 4; idx < 64 * 128; idx += 1024) {
        int k = idx >> 7, c = idx & 127;
        int jj = cy * 128 + c;
        const float* src = (jj < 256) ? (W1 + (size_t)k * 256 + jj)
                                      : (W1 + (size_t)(64 + k) * 256 + (jj - 256));
        *(float4*)&Bs[k][c] = *(const float4*)src;
    }
    __syncthreads();

    const int cgrp = tid & 31;
    const int rgrp = tid >> 5;
    float acc[8][4];
    #pragma unroll
    for (int r = 0; r < 8; ++r) { acc[r][0]=0.f; acc[r][1]=0.f; acc[r][2]=0.f; acc[r][3]=0.f; }

    #pragma unroll 8
    for (int k = 0; k < 64; ++k) {
        float4 b = *(const float4*)&Bs[k][cgrp * 4];
        const float4* ap = (const float4*)&As[k][rgrp * 8];
        float4 a01 = ap[0], a23 = ap[1];
        float av[8] = {a01.x, a01.y, a01.z, a01.w, a23.x, a23.y, a23.z, a23.w};
        #pragma unroll
        for (int r = 0; r < 8; ++r) {
            acc[r][0] = fmaf(av[r], b.x, acc[r][0]);
            acc[r][1] = fmaf(av[r], b.y, acc[r][1]);
            acc[r][2] = fmaf(av[r], b.z, acc[r][2]);
            acc[r][3] = fmaf(av[r], b.w, acc[r][3]);
        }
    }

    const int jj0 = cy * 128 + cgrp * 4;
    float4 badd = {0.f, 0.f, 0.f, 0.f};
    if (jj0 < 256) badd = *(const float4*)(b1 + jj0);
    #pragma unroll
    for (int r = 0; r < 8; ++r) {
        int v = v0 + rgrp * 8 + r;
        if (v < N_NODES) {
            float4 o = {acc[r][0] + badd.x, acc[r][1] + badd.y,
                        acc[r][2] + badd.z, acc[r][3] + badd.w};
            *(float4*)(PQ + (size_t)v * 512 + jj0) = o;
        }
    }
}

// ---------- K2: per-edge score, 4 edges per wave iteration (ILP) ----------
__global__ __launch_bounds__(256) void k2_edge(const float* __restrict__ PQ,
                                               const int* __restrict__ ei,
                                               const int* __restrict__ batch,
                                               const float* __restrict__ W2,
                                               const float* __restrict__ b2,
                                               float* __restrict__ att,
                                               unsigned* __restrict__ deg,
                                               unsigned* __restrict__ minmax) {
    __shared__ unsigned hist[512];
    const int tid = threadIdx.x;
    hist[tid] = 0; hist[tid + 256] = 0;
    __syncthreads();

    const int lane = tid & 63;
    const int wid  = (blockIdx.x * 256 + tid) >> 6;
    const int nw   = (gridDim.x * 256) >> 6;
    const int j0   = lane * 4;
    const float4 w2v = *(const float4*)(W2 + j0);
    const float b2v = b2[0];
    float vmin = __builtin_inff(), vmax = -__builtin_inff();

    // 4 | N_EDGES, so every quad is fully valid
    for (int e0 = wid * 4; e0 < N_EDGES; e0 += nw * 4) {
        int4 rv = *(const int4*)(ei + e0);               // wave-uniform broadcast
        int4 cv = *(const int4*)(ei + N_EDGES + e0);
        const int r0 = rv.x, r1 = rv.y, r2 = rv.z, r3 = rv.w;
        const int c0 = cv.x, c1 = cv.y, c2 = cv.z, c3 = cv.w;

        float4 p0 = *(const float4*)(PQ + (size_t)r0 * 512 + j0);
        float4 p1 = *(const float4*)(PQ + (size_t)r1 * 512 + j0);
        float4 p2 = *(const float4*)(PQ + (size_t)r2 * 512 + j0);
        float4 p3 = *(const float4*)(PQ + (size_t)r3 * 512 + j0);
        float4 q0 = *(const float4*)(PQ + (size_t)c0 * 512 + 256 + j0);
        float4 q1 = *(const float4*)(PQ + (size_t)c1 * 512 + 256 + j0);
        float4 q2 = *(const float4*)(PQ + (size_t)c2 * 512 + 256 + j0);
        float4 q3 = *(const float4*)(PQ + (size_t)c3 * 512 + 256 + j0);

        float part0, part1, part2, part3;
        {
            float s0 = fmaxf(p0.x + q0.x, 0.f), s1 = fmaxf(p0.y + q0.y, 0.f);
            float s2 = fmaxf(p0.z + q0.z, 0.f), s3 = fmaxf(p0.w + q0.w, 0.f);
            part0 = fmaf(s3, w2v.w, fmaf(s2, w2v.z, fmaf(s1, w2v.y, s0 * w2v.x)));
        }
        {
            float s0 = fmaxf(p1.x + q1.x, 0.f), s1 = fmaxf(p1.y + q1.y, 0.f);
            float s2 = fmaxf(p1.z + q1.z, 0.f), s3 = fmaxf(p1.w + q1.w, 0.f);
            part1 = fmaf(s3, w2v.w, fmaf(s2, w2v.z, fmaf(s1, w2v.y, s0 * w2v.x)));
        }
        {
            float s0 = fmaxf(p2.x + q2.x, 0.f), s1 = fmaxf(p2.y + q2.y, 0.f);
            float s2 = fmaxf(p2.z + q2.z, 0.f), s3 = fmaxf(p2.w + q2.w, 0.f);
            part2 = fmaf(s3, w2v.w, fmaf(s2, w2v.z, fmaf(s1, w2v.y, s0 * w2v.x)));
        }
        {
            float s0 = fmaxf(p3.x + q3.x, 0.f), s1 = fmaxf(p3.y + q3.y, 0.f);
            float s2 = fmaxf(p3.z + q3.z, 0.f), s3 = fmaxf(p3.w + q3.w, 0.f);
            part3 = fmaf(s3, w2v.w, fmaf(s2, w2v.z, fmaf(s1, w2v.y, s0 * w2v.x)));
        }
        #pragma unroll
        for (int off = 32; off; off >>= 1) {
            part0 += __shfl_xor(part0, off, 64);
            part1 += __shfl_xor(part1, off, 64);
            part2 += __shfl_xor(part2, off, 64);
            part3 += __shfl_xor(part3, off, 64);
        }
        float a0 = part0 + b2v, a1 = part1 + b2v, a2 = part2 + b2v, a3 = part3 + b2v;
        vmin = fminf(fminf(fminf(vmin, a0), fminf(a1, a2)), a3);
        vmax = fmaxf(fmaxf(fmaxf(vmax, a0), fmaxf(a1, a2)), a3);
        if (lane == 0)      { att[e0]     = a0; atomicAdd(&hist[batch[r0]], 1u); }
        else if (lane == 1) { att[e0 + 1] = a1; atomicAdd(&hist[batch[r1]], 1u); }
        else if (lane == 2) { att[e0 + 2] = a2; atomicAdd(&hist[batch[r2]], 1u); }
        else if (lane == 3) { att[e0 + 3] = a3; atomicAdd(&hist[batch[r3]], 1u); }
    }
    if (lane == 0) {
        atomicMin(&minmax[0], f2sort(vmin));
        atomicMax(&minmax[1], f2sort(vmax));
    }
    __syncthreads();
    atomicAdd(&deg[tid],       hist[tid]);
    atomicAdd(&deg[tid + 256], hist[tid + 256]);
}

// ---------- K3: scan over 512 graph degrees ----------
__global__ __launch_bounds__(512) void k3_scan(const unsigned* __restrict__ deg,
                                               unsigned* __restrict__ start,
                                               unsigned* __restrict__ kk) {
    __shared__ unsigned lds[512];
    int t = threadIdx.x;
    unsigned d = deg[t];
    lds[t] = d;
    for (int off = 1; off < 512; off <<= 1) {
        __syncthreads();
        unsigned v = (t >= off) ? lds[t - off] : 0u;
        __syncthreads();
        lds[t] += v;
    }
    __syncthreads();
    start[t] = lds[t] - d;        // exclusive prefix
    kk[t]    = (d + 1u) >> 1;     // ceil(0.5*deg)
}

// ---------- K4: scatter edges into per-graph buckets with sortable keys ----------
__global__ __launch_bounds__(256) void k4_scatter(const float* __restrict__ att,
                                                  const int* __restrict__ ei,
                                                  const int* __restrict__ batch,
                                                  const unsigned* __restrict__ start,
                                                  unsigned* __restrict__ cursor,
                                                  const unsigned* __restrict__ minmax,
                                                  unsigned long long* __restrict__ bucket) {
    int e = blockIdx.x * 256 + threadIdx.x;
    if (e >= N_EDGES) return;
    float fmin = sort2f(minmax[0]);
    float fmax = sort2f(minmax[1]);
    float denom = (fmax - fmin) + 1e-12f;
    int g = batch[ei[e]];
    float nq = (att[e] - fmin) / denom;        // replicate ref f32 division
    float mq = nq - (float)g;                  // replicate ref's quantizing subtraction
    unsigned key = ~f2sort(mq);                // descending mq under ascending sort
    unsigned pos = atomicAdd(&cursor[g], 1u);
    bucket[start[g] + pos] = ((unsigned long long)key << 32) | (unsigned)e;
}

// ---------- K5: per-graph bitonic sort + keep bits + endpoint flags (fused k6) ----------
__global__ __launch_bounds__(256) void k5_sort(const unsigned* __restrict__ deg,
                                               const unsigned* __restrict__ start,
                                               const unsigned* __restrict__ kk,
                                               const unsigned long long* __restrict__ bucket,
                                               const int* __restrict__ ei,
                                               unsigned char* __restrict__ keep,
                                               unsigned char* __restrict__ flagC,
                                               unsigned char* __restrict__ flagS) {
    __shared__ unsigned long long key[4096];
    const int g = blockIdx.x, t = threadIdx.x;
    unsigned n = deg[g]; if (n > 4096u) n = 4096u;
    const int NS = (n <= 2048u) ? 2048 : 4096;   // adaptive network size
    const unsigned st = start[g];
    for (int i = t; i < NS; i += 256)
        key[i] = ((unsigned)i < n) ? bucket[st + i] : ~0ULL;
    int K = (int)kk[g]; if (K > (int)n) K = (int)n;

    for (int size = 2; size <= NS; size <<= 1)
        for (int stride = size >> 1; stride > 0; stride >>= 1) {
            __syncthreads();
            for (int i = t; i < NS; i += 256) {
                int p = i ^ stride;
                if (p > i) {
                    bool up = ((i & size) == 0);
                    unsigned long long a = key[i], b = key[p];
                    if ((a > b) == up) { key[i] = b; key[p] = a; }
                }
            }
        }
    __syncthreads();
    for (int i = t; i < (int)n; i += 256) {
        unsigned e = (unsigned)(key[i] & 0xFFFFFFFFull);
        int r = ei[e], c = ei[N_EDGES + e];
        if (i < K) {
            keep[e] = 1;
            flagC[r] = 1; flagC[c] = 1;
        } else {
            keep[e] = 0;
            flagS[r] = 1; flagS[c] = 1;
        }
    }
}

// ---------- K7: node-id compaction scan (block 0 = causal, block 1 = spurious) ----------
__global__ __launch_bounds__(1024) void k7_nodescan(const unsigned char* __restrict__ flagC,
                                                    const unsigned char* __restrict__ flagS,
                                                    int* __restrict__ nidxC,
                                                    int* __restrict__ nidxS) {
    const unsigned char* fl = blockIdx.x ? flagS : flagC;
    int* nx = blockIdx.x ? nidxS : nidxC;
    __shared__ int lds[1024];
    const int t = threadIdx.x;
    const int CH = (N_NODES + 1023) / 1024;   // 49
    const int base = t * CH;
    int s = 0;
    for (int i = 0; i < CH; ++i) { int v = base + i; if (v < N_NODES) s += fl[v]; }
    lds[t] = s;
    for (int off = 1; off < 1024; off <<= 1) {
        __syncthreads();
        int v = (t >= off) ? lds[t - off] : 0;
        __syncthreads();
        lds[t] += v;
    }
    __syncthreads();
    int run = lds[t] - s;   // exclusive prefix
    for (int i = 0; i < CH; ++i) {
        int v = base + i;
        if (v < N_NODES) {
            if (fl[v]) { nx[v] = run; run++; } else nx[v] = -1;
        }
    }
}

// ---------- K8: write all outputs (as float32 values) ----------
__global__ __launch_bounds__(256) void k8_out(const float* __restrict__ att,
                                              const unsigned char* __restrict__ keep,
                                              const int* __restrict__ ei,
                                              const int* __restrict__ nidxC,
                                              const int* __restrict__ nidxS,
                                              float* __restrict__ out) {
    int e = blockIdx.x * 256 + threadIdx.x;
    if (e >= N_EDGES) return;
    float a = att[e];
    int kp = keep[e];
    int r = ei[e], c = ei[N_EDGES + e];
    out[e]                = a;
    out[N_EDGES + e]      = kp ? a : 0.f;
    out[2 * N_EDGES + e]  = kp ? 0.f : -a;
    out[3 * N_EDGES + e]  = kp ? (float)nidxC[r] : -1.f;
    out[4 * N_EDGES + e]  = kp ? (float)nidxC[c] : -1.f;
    out[5 * N_EDGES + e]  = kp ? -1.f : (float)nidxS[r];
    out[6 * N_EDGES + e]  = kp ? -1.f : (float)nidxS[c];
}

extern "C" void kernel_launch(void* const* d_in, const int* in_sizes, int n_in,
                              void* d_out, int out_size, void* d_ws, size_t ws_size,
                              hipStream_t stream) {
    const float* emb   = (const float*)d_in[0];
    const int*   ei    = (const int*)d_in[1];
    const int*   batch = (const int*)d_in[2];
    const float* W1    = (const float*)d_in[3];
    const float* b1    = (const float*)d_in[4];
    const float* W2    = (const float*)d_in[5];
    const float* b2    = (const float*)d_in[6];
    float* out = (float*)d_out;

    char* ws = (char*)d_ws;
    size_t off = 0;
    auto alloc = [&](size_t bytes) -> void* {
        off = (off + 255) & ~(size_t)255;
        void* p = ws + off;
        off += bytes;
        return p;
    };

    float* PQ                  = (float*)alloc((size_t)N_NODES * 512 * 4);  // 102.4 MB
    float* att                 = (float*)alloc((size_t)N_EDGES * 4);
    unsigned long long* bucket = (unsigned long long*)alloc((size_t)N_EDGES * 8);
    unsigned char* keep        = (unsigned char*)alloc(N_EDGES);
    unsigned char* flagC       = (unsigned char*)alloc(N_NODES);
    unsigned char* flagS       = (unsigned char*)alloc(N_NODES);
    int* nidxC                 = (int*)alloc((size_t)N_NODES * 4);
    int* nidxS                 = (int*)alloc((size_t)N_NODES * 4);
    unsigned* deg              = (unsigned*)alloc(512 * 4);
    unsigned* start            = (unsigned*)alloc(512 * 4);
    unsigned* kk               = (unsigned*)alloc(512 * 4);
    unsigned* cursor           = (unsigned*)alloc(512 * 4);
    unsigned* minmax           = (unsigned*)alloc(8);

    const int EB = (N_EDGES + 255) / 256;   // 3125
    const int NB = (N_NODES + 255) / 256;   // 196

    k0_init<<<NB, 256, 0, stream>>>(flagC, flagS, deg, cursor, minmax);

    dim3 g1((N_NODES + 63) / 64, 4);
    k1_gemm<<<g1, 256, 0, stream>>>(emb, W1, b1, PQ);
    k2_edge<<<2048, 256, 0, stream>>>(PQ, ei, batch, W2, b2, att, deg, minmax);

    k3_scan<<<1, 512, 0, stream>>>(deg, start, kk);
    k4_scatter<<<EB, 256, 0, stream>>>(att, ei, batch, start, cursor, minmax, bucket);
    k5_sort<<<N_GRAPHS, 256, 0, stream>>>(deg, start, kk, bucket, ei, keep, flagC, flagS);
    k7_nodescan<<<2, 1024, 0, stream>>>(flagC, flagS, nidxC, nidxS);
    k8_out<<<EB, 256, 0, stream>>>(att, keep, ei, nidxC, nidxS, out);
}